// Round 2
// baseline (436.205 us; speedup 1.0000x reference)
//
#include <hip/hip_runtime.h>
#include <math.h>

// Multi-scale region distillation loss — v4 (pixel-per-thread restructure).
// v3 post-mortem: sched_barrier(0) forced 32 VGPRs of float4 loads live; RA
// allocated 40 VGPRs and spilled -> WRITE_SIZE 0.25->100 MB of scratch
// round-trips, net slower. v4 makes deep MLP register-cheap instead:
//   * thread <-> pixel. 3 accumulator registers (dot, |f|^2, |fo|^2).
//   * channel loop unrolled x8: 16 independent dword loads in flight = only
//     16 VGPRs -> compiler clusters them naturally, no spill possible.
//   * consecutive threads = consecutive pixels -> 256 B/wave contiguous.
//   * no cross-wave combine: no shuffles, no LDS partials, no serial tail.
// Grid: 1360 blocks x 128 threads = 174080 threads = total pixels.
//   [0,1024) s0, [1024,1280) s1, [1280,1344) s2, [1344,1360) s3.

#define EPSV 1e-8f

__global__ __launch_bounds__(128)
void msrd_main(const float* __restrict__ f0, const float* __restrict__ fo0,
               const float* __restrict__ f1, const float* __restrict__ fo1,
               const float* __restrict__ f2, const float* __restrict__ fo2,
               const float* __restrict__ f3, const float* __restrict__ fo3,
               const int*   __restrict__ labels,
               const int*   __restrict__ p_nclass,
               float* __restrict__ ws)
{
    const int bid = blockIdx.x;
    int scale, lb, logW, logHW, sshift;
    const float *f, *fo;
    if (bid < 1024)      { scale = 0; lb = bid;        f = f0; fo = fo0; logW = 7; logHW = 14; sshift = 2; }
    else if (bid < 1280) { scale = 1; lb = bid - 1024; f = f1; fo = fo1; logW = 6; logHW = 12; sshift = 3; }
    else if (bid < 1344) { scale = 2; lb = bid - 1280; f = f2; fo = fo2; logW = 5; logHW = 10; sshift = 4; }
    else                 { scale = 3; lb = bid - 1344; f = f3; fo = fo3; logW = 4; logHW = 8;  sshift = 5; }
    const int W   = 1 << logW;
    const int HW  = 1 << logHW;
    const int tid = threadIdx.x;

    const int pix = lb * 128 + tid;      // flat pixel index within scale (b*HW + rem)
    const int b   = pix >> logHW;        // 128 | HW for all scales -> block stays in one image
    const int rem = pix & (HW - 1);

    const float* __restrict__ fp  = f  + (((size_t)(b * 256)) << logHW) + rem;
    const float* __restrict__ fop = fo + (((size_t)(b * 256)) << logHW) + rem;
    const size_t cs = (size_t)HW;        // channel stride in floats

    float d = 0.f, a = 0.f, bn = 0.f;

    // 256 channels = 32 iterations x 8-channel unroll (16 dword loads in flight).
    for (int it = 0; it < 32; ++it) {
        float X[8], Y[8];
        #pragma unroll
        for (int j = 0; j < 8; ++j) X[j] = fp[(size_t)j * cs];
        #pragma unroll
        for (int j = 0; j < 8; ++j) Y[j] = fop[(size_t)j * cs];
        #pragma unroll
        for (int j = 0; j < 8; ++j) {
            d  = fmaf(X[j], Y[j], d);
            a  = fmaf(X[j], X[j], a);
            bn = fmaf(Y[j], Y[j], bn);
        }
        fp  += cs * 8;
        fop += cs * 8;
    }

    __shared__ float bin_sim[32], bin_cnt[32];
    if (tid < 32) { bin_sim[tid] = 0.f; bin_cnt[tid] = 0.f; }
    __syncthreads();

    {
        float na  = fmaxf(sqrtf(a),  EPSV);
        float nb  = fmaxf(sqrtf(bn), EPSV);
        float sim = d / (na * nb);
        const int h   = rem >> logW;
        const int col = rem & (W - 1);
        // nearest-neighbor label: src = dst << sshift (512/H is a power of two)
        const int lidx = (b << 18) + ((h << sshift) << 9) + (col << sshift);
        const int lab  = labels[lidx];
        const int nclass = *p_nclass;
        if ((unsigned)lab < (unsigned)(nclass < 32 ? nclass : 32)) {
            atomicAdd(&bin_sim[lab], sim);
            atomicAdd(&bin_cnt[lab], 1.0f);
        }
    }
    __syncthreads();

    if (tid < 32) {
        float s = bin_sim[tid], c = bin_cnt[tid];
        if (s != 0.f || c != 0.f) {
            atomicAdd(&ws[scale * 64 + tid],      s);
            atomicAdd(&ws[scale * 64 + 32 + tid], c);
        }
    }
}

__global__ void msrd_final(const float* __restrict__ ws,
                           const int* __restrict__ p_nclass,
                           const int* __restrict__ p_nold,
                           float* __restrict__ out)
{
    if (threadIdx.x == 0 && blockIdx.x == 0) {
        const int nc = *p_nclass;
        const int no = *p_nold;
        const float wgt[4] = {1.f, 2.f, 3.f, 4.f};
        float loss = 0.f;
        for (int s = 0; s < 4; ++s) {
            float sl = 0.f;
            for (int c = 0; c < nc && c < 32; ++c) {
                float seg = ws[s * 64 + c];
                float cnt = ws[s * 64 + 32 + c];
                if (cnt > 0.f) {
                    float factor = (c == 0) ? (float)no / (float)nc
                                            : (c <= no ? 1.f : 0.f);
                    sl += factor * (1.f - seg / fmaxf(cnt, 1.f));
                }
            }
            loss += wgt[s] * sl;
        }
        out[0] = loss;
    }
}

extern "C" void kernel_launch(void* const* d_in, const int* in_sizes, int n_in,
                              void* d_out, int out_size, void* d_ws, size_t ws_size,
                              hipStream_t stream) {
    // setup_inputs order: pseudo_labels, f0, fo0, f1, fo1, f2, fo2, f3, fo3, num_class, num_old_class
    const int*   labels = (const int*)  d_in[0];
    const float* f0  = (const float*)d_in[1];
    const float* fo0 = (const float*)d_in[2];
    const float* f1  = (const float*)d_in[3];
    const float* fo1 = (const float*)d_in[4];
    const float* f2  = (const float*)d_in[5];
    const float* fo2 = (const float*)d_in[6];
    const float* f3  = (const float*)d_in[7];
    const float* fo3 = (const float*)d_in[8];
    const int* p_nclass = (const int*)d_in[9];
    const int* p_nold   = (const int*)d_in[10];
    float* out = (float*)d_out;
    float* ws  = (float*)d_ws;

    hipMemsetAsync(ws, 0, 4 * 64 * sizeof(float), stream);
    msrd_main<<<dim3(1360), dim3(128), 0, stream>>>(f0, fo0, f1, fo1, f2, fo2, f3, fo3,
                                                    labels, p_nclass, ws);
    msrd_final<<<dim3(1), dim3(64), 0, stream>>>(ws, p_nclass, p_nold, out);
}

// Round 4
// 360.905 us; speedup vs baseline: 1.2086x; 1.2086x over previous
//
#include <hip/hip_runtime.h>
#include <math.h>

// Multi-scale region distillation loss — v5b (v3 structure, register cap fixed,
// 2-deep software pipeline; v5 macro-parameter-capture bug fixed).
// v3 post-mortem: __launch_bounds__(256,6) capped VGPRs at 256/6≈40 -> the
// sched_barrier-pinned 32-VGPR load batch spilled (WRITE_SIZE 100 MB). v4
// post-mortem: thread-per-pixel had too few waves (2720) and scalar loads.
// v5: 256 thr/4 waves, 32 float4 pixel-groups, 8-way channel split (wave x
// half), 1360 blocks = 5440 waves (21/CU). launch_bounds(256,2) -> cap 128.
// Loads double-buffered A/B: LD0,LD1,C0,LD2,C1,...,C7 pinned by
// sched_barrier(0) between every group -> 8-16 float4 loads permanently in
// flight per wave.

#define EPSV 1e-8f
#define SBAR() __builtin_amdgcn_sched_barrier(0)

#define LOAD_BATCH(X0_,X1_,X2_,X3_,Y0_,Y1_,Y2_,Y3_, koff)                    \
  { const float* _pf = fpb + (koff); const float* _pq = fopb + (koff);       \
    X0_ = *(const float4*)(_pf);                                             \
    X1_ = *(const float4*)(_pf + cs);                                        \
    X2_ = *(const float4*)(_pf + 2*cs);                                      \
    X3_ = *(const float4*)(_pf + 3*cs);                                      \
    Y0_ = *(const float4*)(_pq);                                             \
    Y1_ = *(const float4*)(_pq + cs);                                        \
    Y2_ = *(const float4*)(_pq + 2*cs);                                      \
    Y3_ = *(const float4*)(_pq + 3*cs); }

// NOTE: macro params must not be named x/y/z/w — preprocessor substitutes
// identifier tokens even after '.', which is what broke v5 (x.y -> AX1.AY1).
#define FMA1(Xv,Yv)                                                          \
    dx = fmaf(Xv.x, Yv.x, dx); dy = fmaf(Xv.y, Yv.y, dy);                    \
    dz = fmaf(Xv.z, Yv.z, dz); dw = fmaf(Xv.w, Yv.w, dw);                    \
    ax = fmaf(Xv.x, Xv.x, ax); ay = fmaf(Xv.y, Xv.y, ay);                    \
    az = fmaf(Xv.z, Xv.z, az); aw = fmaf(Xv.w, Xv.w, aw);                    \
    bx = fmaf(Yv.x, Yv.x, bx); by = fmaf(Yv.y, Yv.y, by);                    \
    bz = fmaf(Yv.z, Yv.z, bz); bw = fmaf(Yv.w, Yv.w, bw);

#define CONSUME(X0_,X1_,X2_,X3_,Y0_,Y1_,Y2_,Y3_)                             \
    FMA1(X0_, Y0_) FMA1(X1_, Y1_) FMA1(X2_, Y2_) FMA1(X3_, Y3_)

__global__ __launch_bounds__(256, 2)
void msrd_main(const float* __restrict__ f0, const float* __restrict__ fo0,
               const float* __restrict__ f1, const float* __restrict__ fo1,
               const float* __restrict__ f2, const float* __restrict__ fo2,
               const float* __restrict__ f3, const float* __restrict__ fo3,
               const int*   __restrict__ labels,
               const int*   __restrict__ p_nclass,
               float* __restrict__ ws)
{
    int bid = blockIdx.x;
    int scale, lb, logW, logHW, sshift;
    const float *f, *fo;
    // blocks (32 groups each): [0,1024) s0, [1024,1280) s1, [1280,1344) s2, [1344,1360) s3
    if (bid < 1024)      { scale = 0; lb = bid;        f = f0; fo = fo0; logW = 7; logHW = 14; sshift = 2; }
    else if (bid < 1280) { scale = 1; lb = bid - 1024; f = f1; fo = fo1; logW = 6; logHW = 12; sshift = 3; }
    else if (bid < 1344) { scale = 2; lb = bid - 1280; f = f2; fo = fo2; logW = 5; logHW = 10; sshift = 4; }
    else                 { scale = 3; lb = bid - 1344; f = f3; fo = fo3; logW = 4; logHW = 8;  sshift = 5; }
    const int HW = 1 << logHW;
    const int W  = 1 << logW;

    const int tid  = threadIdx.x;
    const int wave = tid >> 6;    // 0..3
    const int lane = tid & 63;
    const int half = lane >> 5;   // which 16-channel half of the wave's 32-chan chunk
    const int gi   = lane & 31;   // pixel-group index within block

    const int g   = lb * 32 + gi;     // pixel-group index within scale
    const int pix = g << 2;           // flat pixel base (b*HW + h*W + w), w % 4 == 0
    const int b   = pix >> logHW;     // whole half-wave stays within one image
    const int rem = pix & (HW - 1);

    // channels [c0, c0+16) in batches 0-3, [c0+128, c0+144) in batches 4-7
    const int c0 = wave * 32 + half * 16;
    const float* __restrict__ fpb  = f  + (((size_t)(b * 256 + c0)) << logHW) + rem;
    const float* __restrict__ fopb = fo + (((size_t)(b * 256 + c0)) << logHW) + rem;
    const size_t cs = (size_t)HW;     // channel stride in floats

    float dx=0.f,dy=0.f,dz=0.f,dw=0.f;
    float ax=0.f,ay=0.f,az=0.f,aw=0.f;
    float bx=0.f,by=0.f,bz=0.f,bw=0.f;

    float4 AX0,AX1,AX2,AX3, AY0,AY1,AY2,AY3;
    float4 BX0,BX1,BX2,BX3, BY0,BY1,BY2,BY3;

    // batch offsets (floats): k=0..3 -> 4k*cs ; k=4..7 -> (128+4(k-4))*cs
    LOAD_BATCH(AX0,AX1,AX2,AX3, AY0,AY1,AY2,AY3, (size_t)0);        SBAR();
    LOAD_BATCH(BX0,BX1,BX2,BX3, BY0,BY1,BY2,BY3, (size_t)4*cs);     SBAR();
    CONSUME(AX0,AX1,AX2,AX3, AY0,AY1,AY2,AY3);                      SBAR();
    LOAD_BATCH(AX0,AX1,AX2,AX3, AY0,AY1,AY2,AY3, (size_t)8*cs);     SBAR();
    CONSUME(BX0,BX1,BX2,BX3, BY0,BY1,BY2,BY3);                      SBAR();
    LOAD_BATCH(BX0,BX1,BX2,BX3, BY0,BY1,BY2,BY3, (size_t)12*cs);    SBAR();
    CONSUME(AX0,AX1,AX2,AX3, AY0,AY1,AY2,AY3);                      SBAR();
    LOAD_BATCH(AX0,AX1,AX2,AX3, AY0,AY1,AY2,AY3, (size_t)128*cs);   SBAR();
    CONSUME(BX0,BX1,BX2,BX3, BY0,BY1,BY2,BY3);                      SBAR();
    LOAD_BATCH(BX0,BX1,BX2,BX3, BY0,BY1,BY2,BY3, (size_t)132*cs);   SBAR();
    CONSUME(AX0,AX1,AX2,AX3, AY0,AY1,AY2,AY3);                      SBAR();
    LOAD_BATCH(AX0,AX1,AX2,AX3, AY0,AY1,AY2,AY3, (size_t)136*cs);   SBAR();
    CONSUME(BX0,BX1,BX2,BX3, BY0,BY1,BY2,BY3);                      SBAR();
    LOAD_BATCH(BX0,BX1,BX2,BX3, BY0,BY1,BY2,BY3, (size_t)140*cs);   SBAR();
    CONSUME(AX0,AX1,AX2,AX3, AY0,AY1,AY2,AY3);                      SBAR();
    CONSUME(BX0,BX1,BX2,BX3, BY0,BY1,BY2,BY3);

    // combine 16-channel halves: xor-32 butterfly over the 12 partials
    dx += __shfl_xor(dx, 32); dy += __shfl_xor(dy, 32);
    dz += __shfl_xor(dz, 32); dw += __shfl_xor(dw, 32);
    ax += __shfl_xor(ax, 32); ay += __shfl_xor(ay, 32);
    az += __shfl_xor(az, 32); aw += __shfl_xor(aw, 32);
    bx += __shfl_xor(bx, 32); by += __shfl_xor(by, 32);
    bz += __shfl_xor(bz, 32); bw += __shfl_xor(bw, 32);

    __shared__ float4 sD[4][32], sA[4][32], sB[4][32];
    __shared__ float bin_sim[32], bin_cnt[32];
    if (tid < 32) { bin_sim[tid] = 0.f; bin_cnt[tid] = 0.f; }
    if (half == 0) {
        sD[wave][gi] = make_float4(dx,dy,dz,dw);
        sA[wave][gi] = make_float4(ax,ay,az,aw);
        sB[wave][gi] = make_float4(bx,by,bz,bw);
    }
    __syncthreads();

    if (tid < 32) {  // wave 0, half 0: lane gi finalizes group gi (its own b/rem)
        float4 D = sD[0][gi], A = sA[0][gi], Bv = sB[0][gi];
        #pragma unroll
        for (int w = 1; w < 4; ++w) {
            float4 t;
            t = sD[w][gi]; D.x += t.x; D.y += t.y; D.z += t.z; D.w += t.w;
            t = sA[w][gi]; A.x += t.x; A.y += t.y; A.z += t.z; A.w += t.w;
            t = sB[w][gi]; Bv.x += t.x; Bv.y += t.y; Bv.z += t.z; Bv.w += t.w;
        }
        const int nclass  = *p_nclass;
        const int labbase = b << 18;  // b * 512 * 512
        float Dv[4] = {D.x, D.y, D.z, D.w};
        float Av[4] = {A.x, A.y, A.z, A.w};
        float Bw[4] = {Bv.x, Bv.y, Bv.z, Bv.w};
        #pragma unroll
        for (int j = 0; j < 4; ++j) {
            float na  = fmaxf(sqrtf(Av[j]), EPSV);
            float nb  = fmaxf(sqrtf(Bw[j]), EPSV);
            float sim = Dv[j] / (na * nb);
            int p    = rem + j;            // stays within row: rem%4==0, W%4==0
            int h    = p >> logW;
            int col  = p & (W - 1);
            int lidx = labbase + ((h << sshift) << 9) + (col << sshift);
            int lab  = labels[lidx];
            if ((unsigned)lab < (unsigned)nclass) {
                atomicAdd(&bin_sim[lab], sim);
                atomicAdd(&bin_cnt[lab], 1.0f);
            }
        }
    }
    __syncthreads();

    if (tid < 32) {
        float s = bin_sim[tid], c = bin_cnt[tid];
        if (s != 0.f || c != 0.f) {
            atomicAdd(&ws[scale * 64 + tid],      s);
            atomicAdd(&ws[scale * 64 + 32 + tid], c);
        }
    }
}

__global__ void msrd_final(const float* __restrict__ ws,
                           const int* __restrict__ p_nclass,
                           const int* __restrict__ p_nold,
                           float* __restrict__ out)
{
    if (threadIdx.x == 0 && blockIdx.x == 0) {
        const int nc = *p_nclass;
        const int no = *p_nold;
        const float wgt[4] = {1.f, 2.f, 3.f, 4.f};
        float loss = 0.f;
        for (int s = 0; s < 4; ++s) {
            float sl = 0.f;
            for (int c = 0; c < nc && c < 32; ++c) {
                float seg = ws[s * 64 + c];
                float cnt = ws[s * 64 + 32 + c];
                if (cnt > 0.f) {
                    float factor = (c == 0) ? (float)no / (float)nc
                                            : (c <= no ? 1.f : 0.f);
                    sl += factor * (1.f - seg / fmaxf(cnt, 1.f));
                }
            }
            loss += wgt[s] * sl;
        }
        out[0] = loss;
    }
}

extern "C" void kernel_launch(void* const* d_in, const int* in_sizes, int n_in,
                              void* d_out, int out_size, void* d_ws, size_t ws_size,
                              hipStream_t stream) {
    // setup_inputs order: pseudo_labels, f0, fo0, f1, fo1, f2, fo2, f3, fo3, num_class, num_old_class
    const int*   labels = (const int*)  d_in[0];
    const float* f0  = (const float*)d_in[1];
    const float* fo0 = (const float*)d_in[2];
    const float* f1  = (const float*)d_in[3];
    const float* fo1 = (const float*)d_in[4];
    const float* f2  = (const float*)d_in[5];
    const float* fo2 = (const float*)d_in[6];
    const float* f3  = (const float*)d_in[7];
    const float* fo3 = (const float*)d_in[8];
    const int* p_nclass = (const int*)d_in[9];
    const int* p_nold   = (const int*)d_in[10];
    float* out = (float*)d_out;
    float* ws  = (float*)d_ws;

    hipMemsetAsync(ws, 0, 4 * 64 * sizeof(float), stream);
    msrd_main<<<dim3(1360), dim3(256), 0, stream>>>(f0, fo0, f1, fo1, f2, fo2, f3, fo3,
                                                    labels, p_nclass, ws);
    msrd_final<<<dim3(1), dim3(64), 0, stream>>>(ws, p_nclass, p_nold, out);
}

// Round 5
// 360.219 us; speedup vs baseline: 1.2109x; 1.0019x over previous
//
#include <hip/hip_runtime.h>
#include <math.h>

// Multi-scale region distillation loss — v6 (access-pattern restructure).
// v2/v3/v5b all converge to 120-125us despite different schedules -> per-wave
// MLP is not the lever; the served-bandwidth cap (~2.8 TB/s delivered) is.
// Common factor: every wave load covered only 512 B (64 lanes split across 2
// channels). v6: all 64 lanes read the SAME channel, lane-consecutive float4
// -> each global_load_dwordx4 is 1 KB fully contiguous (m13-copy pattern),
// and consecutive blocks stitch consecutive pixel ranges of the same planes.
//   block = 512 thr (8 waves) x 256 contiguous pixels; wave w = channels
//   [32w,32w+32); lane l owns pixels po+4l..po+4l+3 (12 accumulator regs).
//   4-channel x 2-tensor load groups (8x1KB in flight) + one sched_barrier
//   per group (v5b recipe: no spill at VGPR 80), no launch_bounds cap.
// Grid: 680 blocks: [0,512) s0, [512,640) s1, [640,672) s2, [672,680) s3.

#define EPSV 1e-8f
#define SBAR() __builtin_amdgcn_sched_barrier(0)

// NOTE: macro params must not be named x/y/z/w (preprocessor substitutes after '.').
#define FMA1(Xv,Yv)                                                          \
    dx = fmaf(Xv.x, Yv.x, dx); dy = fmaf(Xv.y, Yv.y, dy);                    \
    dz = fmaf(Xv.z, Yv.z, dz); dw = fmaf(Xv.w, Yv.w, dw);                    \
    ax = fmaf(Xv.x, Xv.x, ax); ay = fmaf(Xv.y, Xv.y, ay);                    \
    az = fmaf(Xv.z, Xv.z, az); aw = fmaf(Xv.w, Xv.w, aw);                    \
    bx = fmaf(Yv.x, Yv.x, bx); by = fmaf(Yv.y, Yv.y, by);                    \
    bz = fmaf(Yv.z, Yv.z, bz); bw = fmaf(Yv.w, Yv.w, bw);

__global__ __launch_bounds__(512)
void msrd_main(const float* __restrict__ f0, const float* __restrict__ fo0,
               const float* __restrict__ f1, const float* __restrict__ fo1,
               const float* __restrict__ f2, const float* __restrict__ fo2,
               const float* __restrict__ f3, const float* __restrict__ fo3,
               const int*   __restrict__ labels,
               const int*   __restrict__ p_nclass,
               float* __restrict__ ws)
{
    const int bid = blockIdx.x;
    int scale, lb, logW, logHW, sshift;
    const float *f, *fo;
    if (bid < 512)      { scale = 0; lb = bid;       f = f0; fo = fo0; logW = 7; logHW = 14; sshift = 2; }
    else if (bid < 640) { scale = 1; lb = bid - 512; f = f1; fo = fo1; logW = 6; logHW = 12; sshift = 3; }
    else if (bid < 672) { scale = 2; lb = bid - 640; f = f2; fo = fo2; logW = 5; logHW = 10; sshift = 4; }
    else                { scale = 3; lb = bid - 672; f = f3; fo = fo3; logW = 4; logHW = 8;  sshift = 5; }
    const int W = 1 << logW;

    const int tid  = threadIdx.x;
    const int wave = tid >> 6;     // 0..7 -> channel chunk [32w, 32w+32)
    const int lane = tid & 63;     // pixel-group within the block's 256-pixel tile

    const int lbpi = logHW - 8;                    // log2(blocks per image)
    const int img  = lb >> lbpi;
    const int po   = (lb - (img << lbpi)) << 8;    // tile base pixel within image
    const int rem  = po + (lane << 2);             // this lane's first pixel

    const int c0 = wave << 5;
    const float* __restrict__ fp  = f  + (((size_t)(img * 256 + c0)) << logHW) + rem;
    const float* __restrict__ fop = fo + (((size_t)(img * 256 + c0)) << logHW) + rem;
    const size_t cs = (size_t)1 << logHW;          // channel stride in floats

    float dx=0.f,dy=0.f,dz=0.f,dw=0.f;
    float ax=0.f,ay=0.f,az=0.f,aw=0.f;
    float bx=0.f,by=0.f,bz=0.f,bw=0.f;

    // 32 channels per wave, 4-channel groups: 8 x 1KB loads issued per group.
    #pragma unroll
    for (int cc = 0; cc < 32; cc += 4) {
        const float* pf = fp  + (size_t)cc * cs;
        const float* pq = fop + (size_t)cc * cs;
        float4 X0, X1, X2, X3, Y0, Y1, Y2, Y3;
        X0 = *(const float4*)(pf);
        X1 = *(const float4*)(pf + cs);
        X2 = *(const float4*)(pf + 2*cs);
        X3 = *(const float4*)(pf + 3*cs);
        Y0 = *(const float4*)(pq);
        Y1 = *(const float4*)(pq + cs);
        Y2 = *(const float4*)(pq + 2*cs);
        Y3 = *(const float4*)(pq + 3*cs);
        SBAR();   // loads issue before consumption; next group's loads may
                  // interleave with this group's FMAs (2-deep natural pipe)
        FMA1(X0, Y0) FMA1(X1, Y1) FMA1(X2, Y2) FMA1(X3, Y3)
    }

    // cross-wave combine: 8 channel-chunks -> full 256-channel sums per pixel
    __shared__ float4 sD[8][64], sA[8][64], sB[8][64];
    __shared__ float bin_sim[32], bin_cnt[32];
    if (tid < 32) { bin_sim[tid] = 0.f; bin_cnt[tid] = 0.f; }
    sD[wave][lane] = make_float4(dx,dy,dz,dw);
    sA[wave][lane] = make_float4(ax,ay,az,aw);
    sB[wave][lane] = make_float4(bx,by,bz,bw);
    __syncthreads();

    if (tid < 64) {   // wave 0: lane l finalizes its own 4 pixels (same rem)
        float4 D = sD[0][lane], A = sA[0][lane], Bv = sB[0][lane];
        #pragma unroll
        for (int w = 1; w < 8; ++w) {
            float4 t;
            t = sD[w][lane]; D.x += t.x; D.y += t.y; D.z += t.z; D.w += t.w;
            t = sA[w][lane]; A.x += t.x; A.y += t.y; A.z += t.z; A.w += t.w;
            t = sB[w][lane]; Bv.x += t.x; Bv.y += t.y; Bv.z += t.z; Bv.w += t.w;
        }
        const int nclass  = *p_nclass;
        const int labbase = img << 18;   // img * 512 * 512
        float Dv[4] = {D.x, D.y, D.z, D.w};
        float Av[4] = {A.x, A.y, A.z, A.w};
        float Bw[4] = {Bv.x, Bv.y, Bv.z, Bv.w};
        #pragma unroll
        for (int j = 0; j < 4; ++j) {
            float na  = fmaxf(sqrtf(Av[j]), EPSV);
            float nb  = fmaxf(sqrtf(Bw[j]), EPSV);
            float sim = Dv[j] / (na * nb);
            int p    = rem + j;          // stays within row: rem%4==0, W%4==0
            int h    = p >> logW;
            int col  = p & (W - 1);
            int lidx = labbase + ((h << sshift) << 9) + (col << sshift);
            int lab  = labels[lidx];
            if ((unsigned)lab < (unsigned)nclass) {
                atomicAdd(&bin_sim[lab], sim);
                atomicAdd(&bin_cnt[lab], 1.0f);
            }
        }
    }
    __syncthreads();

    if (tid < 32) {
        float s = bin_sim[tid], c = bin_cnt[tid];
        if (s != 0.f || c != 0.f) {
            atomicAdd(&ws[scale * 64 + tid],      s);
            atomicAdd(&ws[scale * 64 + 32 + tid], c);
        }
    }
}

__global__ void msrd_final(const float* __restrict__ ws,
                           const int* __restrict__ p_nclass,
                           const int* __restrict__ p_nold,
                           float* __restrict__ out)
{
    if (threadIdx.x == 0 && blockIdx.x == 0) {
        const int nc = *p_nclass;
        const int no = *p_nold;
        const float wgt[4] = {1.f, 2.f, 3.f, 4.f};
        float loss = 0.f;
        for (int s = 0; s < 4; ++s) {
            float sl = 0.f;
            for (int c = 0; c < nc && c < 32; ++c) {
                float seg = ws[s * 64 + c];
                float cnt = ws[s * 64 + 32 + c];
                if (cnt > 0.f) {
                    float factor = (c == 0) ? (float)no / (float)nc
                                            : (c <= no ? 1.f : 0.f);
                    sl += factor * (1.f - seg / fmaxf(cnt, 1.f));
                }
            }
            loss += wgt[s] * sl;
        }
        out[0] = loss;
    }
}

extern "C" void kernel_launch(void* const* d_in, const int* in_sizes, int n_in,
                              void* d_out, int out_size, void* d_ws, size_t ws_size,
                              hipStream_t stream) {
    // setup_inputs order: pseudo_labels, f0, fo0, f1, fo1, f2, fo2, f3, fo3, num_class, num_old_class
    const int*   labels = (const int*)  d_in[0];
    const float* f0  = (const float*)d_in[1];
    const float* fo0 = (const float*)d_in[2];
    const float* f1  = (const float*)d_in[3];
    const float* fo1 = (const float*)d_in[4];
    const float* f2  = (const float*)d_in[5];
    const float* fo2 = (const float*)d_in[6];
    const float* f3  = (const float*)d_in[7];
    const float* fo3 = (const float*)d_in[8];
    const int* p_nclass = (const int*)d_in[9];
    const int* p_nold   = (const int*)d_in[10];
    float* out = (float*)d_out;
    float* ws  = (float*)d_ws;

    hipMemsetAsync(ws, 0, 4 * 64 * sizeof(float), stream);
    msrd_main<<<dim3(680), dim3(512), 0, stream>>>(f0, fo0, f1, fo1, f2, fo2, f3, fo3,
                                                   labels, p_nclass, ws);
    msrd_final<<<dim3(1), dim3(64), 0, stream>>>(ws, p_nclass, p_nold, out);
}